// Round 15
// baseline (3554.664 us; speedup 1.0000x reference)
//
#include <hip/hip_runtime.h>

#define N_USERS 1000000
#define NEDGE   32000000
#define OUT_F   64
#define BN_EPS  1e-5f

// ---- Pass 1 (proven round-12 scatter): 245 dst-buckets of 4096 ----
#define SBITS     12
#define S_BUCKET  4096
#define NB        245
#define CAP       136896                  // mean 130612 + ~17 sigma, mult of 16
#define SCAT_BLOCKS 1024
#define TILE      4096
#define NTILES    ((NEDGE + TILE - 1) / TILE)

// ---- Pass 2 (regroup): super-buckets x src-windows, LDS-gather hop ----
// Hop is MSHR-bound at ~0.22 L1-miss-lines/cyc/CU (round-12: 232us = exactly
// 32M misses at 64/300cyc). Fix: gathers become ds_read from a staged 16KB
// src-window; records regrouped into (super 24576-dst, window 4096-src)
// segments, COMPACT in d_out (NEDGE*8 == out bytes exactly).
#define SUP_B     6                       // pass-1 buckets per super
#define NSUP      41                      // ceil(245/6); last super = 5 buckets
#define S_SUPER   24576                   // dst nodes per super (acc = 96KB LDS)
#define NWIN      245                     // src windows of 4096 (src>>12)
#define NBINS2    (NSUP * NWIN)           // 10045
#define HSPLIT    6                       // blocks per super in the hop
#define RGRID     1024

static_assert((unsigned long long)NEDGE * 8ull ==
              (unsigned long long)N_USERS * OUT_F * 4ull,
              "compact rec2 must exactly fit d_out");

typedef unsigned int uint4v __attribute__((ext_vector_type(4)));
typedef unsigned int uint2v __attribute__((ext_vector_type(2)));
typedef int          int4v  __attribute__((ext_vector_type(4)));
typedef float        flt4v  __attribute__((ext_vector_type(4)));

// ---------------- pass 1: binned scatter (unchanged from round 12) ----------------

__global__ void init_cursors(unsigned* __restrict__ cursors) {
    int i = blockIdx.x * blockDim.x + threadIdx.x;
    if (i < NB) cursors[i] = (unsigned)i * CAP;
}

__global__ __launch_bounds__(256) void scatter_bin(
    const int* __restrict__ src, const int* __restrict__ dst,
    const float* __restrict__ ew, uint2* __restrict__ rec,
    unsigned* __restrict__ cursors) {
    __shared__ uint2 srec[TILE];
    __shared__ unsigned short sbkt[TILE];
    __shared__ unsigned hist[NB];
    __shared__ unsigned curs[NB];
    __shared__ unsigned gpos[NB];
    __shared__ unsigned chunkT[256];
    int tid = threadIdx.x;

    for (int tile = blockIdx.x; tile < NTILES; tile += gridDim.x) {
        int e0 = tile * TILE;
        int n_this = (e0 + TILE <= NEDGE) ? TILE : (NEDGE - e0);
        int nq = n_this >> 2;
        int q0 = e0 >> 2;

        for (int i = tid; i < NB; i += 256) hist[i] = 0;
        __syncthreads();

        int4v dv[4]; int4v sv[4]; flt4v wv[4];
        #pragma unroll
        for (int k = 0; k < 4; ++k) {
            int q = k * 256 + tid;
            if (q < nq) {
                dv[k] = __builtin_nontemporal_load(reinterpret_cast<const int4v*>(dst) + q0 + q);
                sv[k] = __builtin_nontemporal_load(reinterpret_cast<const int4v*>(src) + q0 + q);
                wv[k] = __builtin_nontemporal_load(reinterpret_cast<const flt4v*>(ew) + q0 + q);
            }
        }
        #pragma unroll
        for (int k = 0; k < 4; ++k) {
            int q = k * 256 + tid;
            if (q < nq) {
                #pragma unroll
                for (int j = 0; j < 4; ++j)
                    atomicAdd(&hist[dv[k][j] >> SBITS], 1u);
            }
        }
        __syncthreads();

        {
            int base = tid * 4;
            unsigned run = 0;
            #pragma unroll
            for (int k = 0; k < 4; ++k) {
                int idx = base + k;
                unsigned v = (idx < NB) ? hist[idx] : 0u;
                if (idx < NB) hist[idx] = run;
                run += v;
            }
            chunkT[tid] = run;
        }
        __syncthreads();
        if (tid == 0) {
            unsigned r = 0;
            for (int t = 0; t < 256; ++t) { unsigned v = chunkT[t]; chunkT[t] = r; r += v; }
        }
        __syncthreads();
        {
            int base = tid * 4;
            unsigned add = chunkT[tid];
            #pragma unroll
            for (int k = 0; k < 4; ++k) {
                int idx = base + k;
                if (idx < NB) hist[idx] += add;
            }
        }
        __syncthreads();

        for (int b = tid; b < NB; b += 256) {
            unsigned st = hist[b];
            unsigned en = (b == NB - 1) ? (unsigned)n_this : hist[b + 1];
            unsigned c = en - st;
            gpos[b] = c ? atomicAdd(&cursors[b], c) : 0u;
            curs[b] = 0;
        }
        __syncthreads();

        #pragma unroll
        for (int k = 0; k < 4; ++k) {
            int q = k * 256 + tid;
            if (q < nq) {
                #pragma unroll
                for (int j = 0; j < 4; ++j) {
                    int dd = dv[k][j], ss = sv[k][j];
                    int b = dd >> SBITS;
                    unsigned p = hist[b] + atomicAdd(&curs[b], 1u);
                    srec[p] = make_uint2(((unsigned)(dd & (S_BUCKET - 1)) << 20) | (unsigned)ss,
                                         __float_as_uint(wv[k][j]));
                    sbkt[p] = (unsigned short)b;
                }
            }
        }
        __syncthreads();

        for (int i = tid; i < n_this; i += 256) {
            unsigned b = sbkt[i];
            rec[gpos[b] + ((unsigned)i - hist[b])] = srec[i];
        }
        __syncthreads();
    }
}

// ---------------- pass 2a: per-(super,window) counts ----------------

__global__ __launch_bounds__(256) void count_bins(
    const uint2* __restrict__ rec, const unsigned* __restrict__ cursors,
    unsigned* __restrict__ cnt2) {
    __shared__ unsigned hist[NWIN];
    int tid = threadIdx.x;
    int b = blockIdx.x >> 2, q = blockIdx.x & 3;
    for (int i = tid; i < NWIN; i += 256) hist[i] = 0;
    __syncthreads();
    unsigned cnt = cursors[b] - (unsigned)b * CAP;
    unsigned lo = (unsigned)(((unsigned long long)cnt * (unsigned)q) >> 2);
    unsigned hi = (q == 3) ? cnt : (unsigned)(((unsigned long long)cnt * (unsigned)(q + 1)) >> 2);
    const uint2v* bp = reinterpret_cast<const uint2v*>(rec + (size_t)b * CAP);
    unsigned i = lo + (unsigned)tid;
    for (; i + 768 < hi; i += 1024) {
        uint2v r0 = __builtin_nontemporal_load(bp + i);
        uint2v r1 = __builtin_nontemporal_load(bp + i + 256);
        uint2v r2 = __builtin_nontemporal_load(bp + i + 512);
        uint2v r3 = __builtin_nontemporal_load(bp + i + 768);
        atomicAdd(&hist[(r0.x & 0xFFFFFu) >> 12], 1u);
        atomicAdd(&hist[(r1.x & 0xFFFFFu) >> 12], 1u);
        atomicAdd(&hist[(r2.x & 0xFFFFFu) >> 12], 1u);
        atomicAdd(&hist[(r3.x & 0xFFFFFu) >> 12], 1u);
    }
    for (; i < hi; i += 256) {
        uint2v r = __builtin_nontemporal_load(bp + i);
        atomicAdd(&hist[(r.x & 0xFFFFFu) >> 12], 1u);
    }
    __syncthreads();
    unsigned base = (unsigned)(b / SUP_B) * (unsigned)NWIN;
    for (int k = tid; k < NWIN; k += 256)
        if (hist[k]) atomicAdd(&cnt2[base + k], hist[k]);
}

// ---------------- pass 2b: exclusive prefix over 10045 bins ----------------

__global__ __launch_bounds__(256) void prefix_bins(
    const unsigned* __restrict__ cnt2, unsigned* __restrict__ bases,
    unsigned* __restrict__ cursors2) {
    __shared__ unsigned chunkT[256];
    int t = threadIdx.x;
    unsigned loc[40];
    unsigned run = 0;
    for (int k = 0; k < 40; ++k) {
        int idx = t * 40 + k;
        unsigned v = (idx < NBINS2) ? cnt2[idx] : 0u;
        loc[k] = run; run += v;
    }
    chunkT[t] = run;
    __syncthreads();
    if (t == 0) {
        unsigned r = 0;
        for (int i = 0; i < 256; ++i) { unsigned v = chunkT[i]; chunkT[i] = r; r += v; }
    }
    __syncthreads();
    unsigned add = chunkT[t];
    for (int k = 0; k < 40; ++k) {
        int idx = t * 40 + k;
        if (idx < NBINS2) { unsigned v = loc[k] + add; bases[idx] = v; cursors2[idx] = v; }
    }
    if (t == 0) bases[NBINS2] = (unsigned)NEDGE;
}

// ---------------- pass 2c: regroup into compact (super,window) segments ----------------
// meta2 = rdst(15b)<<12 | src_local(12b); rdst = (b%6)*4096 + dst_local.

__global__ __launch_bounds__(256) void regroup(
    const uint2* __restrict__ rec, const unsigned* __restrict__ cursors,
    uint2* __restrict__ rec2, unsigned* __restrict__ cursors2) {
    __shared__ uint2 srec[TILE];              // transformed records
    __shared__ unsigned char skey[TILE];
    __shared__ unsigned hist[NWIN];
    __shared__ unsigned curs[NWIN];
    __shared__ unsigned gpos[NWIN];
    __shared__ unsigned chunkT[256];
    int tid = threadIdx.x;

    for (int b = 0; b < NB; ++b) {
        unsigned cntb = cursors[b] - (unsigned)b * CAP;
        unsigned binbase = (unsigned)(b / SUP_B) * (unsigned)NWIN;
        unsigned rb = (unsigned)(b % SUP_B) << 12;
        int ntiles = (int)((cntb + TILE - 1) / TILE);
        const uint2* bp = rec + (size_t)b * CAP;

        for (int t = blockIdx.x; t < ntiles; t += gridDim.x) {
            unsigned e0 = (unsigned)t * TILE;
            unsigned n_this = (cntb - e0 < TILE) ? (cntb - e0) : TILE;

            for (int i = tid; i < NWIN; i += 256) hist[i] = 0;
            __syncthreads();

            uint4v rv[8];                      // 16 records/thread
            #pragma unroll
            for (int k2 = 0; k2 < 8; ++k2) {
                unsigned idx = (unsigned)(k2 * 512 + tid * 2);
                if (idx < n_this)
                    rv[k2] = __builtin_nontemporal_load(
                        reinterpret_cast<const uint4v*>(bp + e0 + idx));
            }
            #pragma unroll
            for (int k2 = 0; k2 < 8; ++k2) {
                unsigned idx = (unsigned)(k2 * 512 + tid * 2);
                if (idx < n_this)     atomicAdd(&hist[(rv[k2].x & 0xFFFFFu) >> 12], 1u);
                if (idx + 1 < n_this) atomicAdd(&hist[(rv[k2].z & 0xFFFFFu) >> 12], 1u);
            }
            __syncthreads();

            chunkT[tid] = (tid < NWIN) ? hist[tid] : 0u;
            __syncthreads();
            if (tid == 0) {
                unsigned r = 0;
                for (int i = 0; i < 256; ++i) { unsigned v = chunkT[i]; chunkT[i] = r; r += v; }
            }
            __syncthreads();
            if (tid < NWIN) hist[tid] = chunkT[tid];
            __syncthreads();
            if (tid < NWIN) {
                unsigned st = hist[tid];
                unsigned en = (tid == NWIN - 1) ? n_this : hist[tid + 1];
                unsigned c = en - st;
                gpos[tid] = c ? atomicAdd(&cursors2[binbase + tid], c) : 0u;
                curs[tid] = 0;
            }
            __syncthreads();

            #pragma unroll
            for (int k2 = 0; k2 < 8; ++k2) {
                unsigned idx = (unsigned)(k2 * 512 + tid * 2);
                if (idx < n_this) {
                    unsigned m = rv[k2].x;
                    unsigned k = (m & 0xFFFFFu) >> 12;
                    unsigned p = hist[k] + atomicAdd(&curs[k], 1u);
                    srec[p] = make_uint2((((m >> 20) + rb) << 12) | (m & 0xFFFu), rv[k2].y);
                    skey[p] = (unsigned char)k;
                }
                if (idx + 1 < n_this) {
                    unsigned m = rv[k2].z;
                    unsigned k = (m & 0xFFFFFu) >> 12;
                    unsigned p = hist[k] + atomicAdd(&curs[k], 1u);
                    srec[p] = make_uint2((((m >> 20) + rb) << 12) | (m & 0xFFFu), rv[k2].w);
                    skey[p] = (unsigned char)k;
                }
            }
            __syncthreads();

            for (unsigned i = (unsigned)tid; i < n_this; i += 256) {
                unsigned k = skey[i];
                rec2[gpos[k] + (i - hist[k])] = srec[i];
            }
            __syncthreads();
        }
    }
}

// ---------------- LDS-gather hop ----------------

__global__ __launch_bounds__(512) void hop_super(
    const uint2* __restrict__ rec2, const unsigned* __restrict__ bases,
    const float* __restrict__ cur, float* __restrict__ nxt) {
    __shared__ float acc[S_SUPER];     // 96KB
    __shared__ float win[4096];        // 16KB
    int tid = threadIdx.x;
    int s = blockIdx.x / HSPLIT;
    int j = blockIdx.x % HSPLIT;
    for (int i = tid; i < S_SUPER; i += 512) acc[i] = 0.0f;

    for (int k = j; k < NWIN; k += HSPLIT) {
        __syncthreads();                       // acc init / prev window consumed
        int wbase = k << 12;
        for (int i = tid; i < 4096; i += 512) {
            int g = wbase + i;
            win[i] = (g < N_USERS) ? cur[g] : 0.0f;
        }
        __syncthreads();

        unsigned lo = bases[s * NWIN + k];
        unsigned hi = bases[s * NWIN + k + 1];   // global-contiguous: valid for all k
        if ((lo & 1u) && lo < hi) {              // align to 16B
            if (tid == 0) {
                uint2 r = rec2[lo];
                atomicAdd(&acc[r.x >> 12], win[r.x & 0xFFFu] * __uint_as_float(r.y));
            }
            ++lo;
        }
        for (unsigned i = lo + 4u * (unsigned)tid; i + 4u <= hi; i += 4u * 512u) {
            uint4v a = __builtin_nontemporal_load(reinterpret_cast<const uint4v*>(rec2 + i));
            uint4v b2 = __builtin_nontemporal_load(reinterpret_cast<const uint4v*>(rec2 + i + 2));
            float v0 = win[a.x & 0xFFFu];
            float v1 = win[a.z & 0xFFFu];
            float v2 = win[b2.x & 0xFFFu];
            float v3 = win[b2.z & 0xFFFu];
            atomicAdd(&acc[a.x >> 12],  v0 * __uint_as_float(a.y));
            atomicAdd(&acc[a.z >> 12],  v1 * __uint_as_float(a.w));
            atomicAdd(&acc[b2.x >> 12], v2 * __uint_as_float(b2.y));
            atomicAdd(&acc[b2.z >> 12], v3 * __uint_as_float(b2.w));
        }
        unsigned tstart = lo + ((hi - lo) & ~3u);
        if (tstart + (unsigned)tid < hi) {
            uint2 r = rec2[tstart + tid];
            atomicAdd(&acc[r.x >> 12], win[r.x & 0xFFFu] * __uint_as_float(r.y));
        }
    }
    __syncthreads();
    int d0 = s * S_SUPER;
    for (int i = tid; i < S_SUPER; i += 512) {
        int n = d0 + i;
        if (n < N_USERS) atomicAdd(&nxt[n], acc[i]);
    }
}

// ---------------- fallback path ----------------

__global__ void zero_kernel(float* __restrict__ p, int n) {
    int i = blockIdx.x * blockDim.x + threadIdx.x;
    int stride = gridDim.x * blockDim.x;
    for (; i < n; i += stride) p[i] = 0.0f;
}

__global__ __launch_bounds__(256) void hop_atomic(
    const int* __restrict__ src, const int* __restrict__ dst,
    const float* __restrict__ ew, const float* __restrict__ cur,
    float* __restrict__ nxt) {
    int e = blockIdx.x * blockDim.x + threadIdx.x;
    if (e * 4 < NEDGE) {
        int4   s = ((const int4*)src)[e];
        int4   d = ((const int4*)dst)[e];
        float4 w = ((const float4*)ew)[e];
        atomicAdd(&nxt[d.x], cur[s.x] * w.x);
        atomicAdd(&nxt[d.y], cur[s.y] * w.y);
        atomicAdd(&nxt[d.z], cur[s.z] * w.z);
        atomicAdd(&nxt[d.w], cur[s.w] * w.w);
    }
}

// ---------------- finalize ----------------

__global__ __launch_bounds__(256) void finalize_kernel(
    const float* __restrict__ x,  const float* __restrict__ f1,
    const float* __restrict__ f2, const float* __restrict__ f3,
    const float* __restrict__ f4, const float* __restrict__ W,
    const float* __restrict__ bias, const float* __restrict__ gamma,
    const float* __restrict__ beta, float* __restrict__ out) {
    int lane = threadIdx.x & 63;
    int waveInBlock = threadIdx.x >> 6;
    int wavesPerBlock = blockDim.x >> 6;
    int gwave  = blockIdx.x * wavesPerBlock + waveInBlock;
    int nwaves = gridDim.x * wavesPerBlock;

    float w0 = W[lane * 5 + 0];
    float w1 = W[lane * 5 + 1];
    float w2 = W[lane * 5 + 2];
    float w3 = W[lane * 5 + 3];
    float w4 = W[lane * 5 + 4];
    float b  = bias[lane];

    for (int n = gwave; n < N_USERS; n += nwaves) {
        float c0 = x[n], c1 = f1[n], c2 = f2[n], c3 = f3[n], c4 = f4[n];
        float y = b + c0 * w0 + c1 * w1 + c2 * w2 + c3 * w3 + c4 * w4;

        float s = y;
        #pragma unroll
        for (int off = 32; off; off >>= 1) s += __shfl_xor(s, off);
        float mean = s * (1.0f / 64.0f);

        float d = y - mean;
        float v = d * d;
        #pragma unroll
        for (int off = 32; off; off >>= 1) v += __shfl_xor(v, off);
        float var = v * (1.0f / 64.0f);

        float o = d * rsqrtf(var + BN_EPS) * gamma[n] + beta[n];
        __builtin_nontemporal_store(o, &out[(size_t)n * OUT_F + lane]);
    }
}

extern "C" void kernel_launch(void* const* d_in, const int* in_sizes, int n_in,
                              void* d_out, int out_size, void* d_ws, size_t ws_size,
                              hipStream_t stream) {
    const float* x     = (const float*)d_in[0];
    const int*   ei    = (const int*)d_in[1];
    const float* ew    = (const float*)d_in[2];
    const float* W     = (const float*)d_in[3];
    const float* bias  = (const float*)d_in[4];
    const float* gamma = (const float*)d_in[5];
    const float* beta  = (const float*)d_in[6];
    float* out = (float*)d_out;

    const int* src = ei;
    const int* dst = ei + NEDGE;

    // Workspace layout (~284.5MB; known-available >= 304MB from rounds 0-1)
    float* f = (float*)d_ws;                                     // 16MB
    uint2* rec = (uint2*)(f + 4ull * N_USERS);                   // 268.3MB
    unsigned* cursors  = (unsigned*)(rec + (size_t)NB * CAP);    // pad 1024
    unsigned* cnt2     = cursors + 1024;                         // pad 10240
    unsigned* bases    = cnt2 + 10240;                           // NBINS2+1, pad 10240
    unsigned* cursors2 = bases + 10240;                          // pad 10240
    size_t needed = 16000000ull + (size_t)NB * CAP * 8 + 4096 + 3ull * 40960;

    // Regrouped compact records live in d_out (dead until finalize).
    uint2* rec2 = (uint2*)d_out;

    if (ws_size >= needed) {
        init_cursors<<<1, 256, 0, stream>>>(cursors);
        zero_kernel<<<2048, 256, 0, stream>>>(f, 4 * N_USERS);      // hop flush is atomicAdd
        zero_kernel<<<40, 256, 0, stream>>>((float*)cnt2, NBINS2);  // bit-zero uints
        scatter_bin<<<SCAT_BLOCKS, 256, 0, stream>>>(src, dst, ew, rec, cursors);
        count_bins<<<NB * 4, 256, 0, stream>>>(rec, cursors, cnt2);
        prefix_bins<<<1, 256, 0, stream>>>(cnt2, bases, cursors2);
        regroup<<<RGRID, 256, 0, stream>>>(rec, cursors, rec2, cursors2);
        const float* cur = x;
        for (int h = 0; h < 4; ++h) {
            float* nxt = f + (size_t)h * N_USERS;
            hop_super<<<NSUP * HSPLIT, 512, 0, stream>>>(rec2, bases, cur, nxt);
            cur = nxt;
        }
    } else {
        zero_kernel<<<4096, 256, 0, stream>>>(f, 4 * N_USERS);
        const float* cur = x;
        for (int h = 0; h < 4; ++h) {
            float* nxt = f + (size_t)h * N_USERS;
            hop_atomic<<<NEDGE / 4 / 256, 256, 0, stream>>>(src, dst, ew, cur, nxt);
            cur = nxt;
        }
    }

    finalize_kernel<<<2048, 256, 0, stream>>>(
        x, f, f + N_USERS, f + 2 * N_USERS, f + 3 * N_USERS,
        W, bias, gamma, beta, out);
}

// Round 16
// 1827.735 us; speedup vs baseline: 1.9448x; 1.9448x over previous
//
#include <hip/hip_runtime.h>

#define N_USERS 1000000
#define NEDGE   32000000
#define OUT_F   64
#define BN_EPS  1e-5f

// ---- Pass 1 (proven round-12 scatter): 245 dst-buckets of 4096 ----
#define SBITS     12
#define S_BUCKET  4096
#define NB        245
#define CAP       136896                  // mean 130612 + ~17 sigma, mult of 16
#define SCAT_BLOCKS 1024
#define TILE      4096
#define NTILES    ((NEDGE + TILE - 1) / TILE)

// ---- Pass 2 (regroup): super-buckets x src-windows, LDS-gather hop ----
#define SUP_B     6                       // pass-1 buckets per super
#define NSUP      41                      // ceil(245/6)
#define S_SUPER   24576                   // dst nodes per super (acc = 96KB LDS)
#define NWIN      245                     // src windows of 4096 (src>>12)
#define NBINS2    (NSUP * NWIN)           // 10045
#define HSPLIT    6                       // blocks per super in the hop
#define RGRID     1024
#define MT        34                      // max tiles per bucket (34*4096 >= CAP)

static_assert((unsigned long long)NEDGE * 8ull ==
              (unsigned long long)N_USERS * OUT_F * 4ull,
              "compact rec2 must exactly fit d_out");

typedef unsigned int uint4v __attribute__((ext_vector_type(4)));
typedef unsigned int uint2v __attribute__((ext_vector_type(2)));
typedef int          int4v  __attribute__((ext_vector_type(4)));
typedef float        flt4v  __attribute__((ext_vector_type(4)));

// ---------------- pass 1: binned scatter (unchanged from round 12) ----------------

__global__ void init_cursors(unsigned* __restrict__ cursors) {
    int i = blockIdx.x * blockDim.x + threadIdx.x;
    if (i < NB) cursors[i] = (unsigned)i * CAP;
}

__global__ __launch_bounds__(256) void scatter_bin(
    const int* __restrict__ src, const int* __restrict__ dst,
    const float* __restrict__ ew, uint2* __restrict__ rec,
    unsigned* __restrict__ cursors) {
    __shared__ uint2 srec[TILE];
    __shared__ unsigned short sbkt[TILE];
    __shared__ unsigned hist[NB];
    __shared__ unsigned curs[NB];
    __shared__ unsigned gpos[NB];
    __shared__ unsigned chunkT[256];
    int tid = threadIdx.x;

    for (int tile = blockIdx.x; tile < NTILES; tile += gridDim.x) {
        int e0 = tile * TILE;
        int n_this = (e0 + TILE <= NEDGE) ? TILE : (NEDGE - e0);
        int nq = n_this >> 2;
        int q0 = e0 >> 2;

        for (int i = tid; i < NB; i += 256) hist[i] = 0;
        __syncthreads();

        int4v dv[4]; int4v sv[4]; flt4v wv[4];
        #pragma unroll
        for (int k = 0; k < 4; ++k) {
            int q = k * 256 + tid;
            if (q < nq) {
                dv[k] = __builtin_nontemporal_load(reinterpret_cast<const int4v*>(dst) + q0 + q);
                sv[k] = __builtin_nontemporal_load(reinterpret_cast<const int4v*>(src) + q0 + q);
                wv[k] = __builtin_nontemporal_load(reinterpret_cast<const flt4v*>(ew) + q0 + q);
            }
        }
        #pragma unroll
        for (int k = 0; k < 4; ++k) {
            int q = k * 256 + tid;
            if (q < nq) {
                #pragma unroll
                for (int j = 0; j < 4; ++j)
                    atomicAdd(&hist[dv[k][j] >> SBITS], 1u);
            }
        }
        __syncthreads();

        {
            int base = tid * 4;
            unsigned run = 0;
            #pragma unroll
            for (int k = 0; k < 4; ++k) {
                int idx = base + k;
                unsigned v = (idx < NB) ? hist[idx] : 0u;
                if (idx < NB) hist[idx] = run;
                run += v;
            }
            chunkT[tid] = run;
        }
        __syncthreads();
        if (tid == 0) {
            unsigned r = 0;
            for (int t = 0; t < 256; ++t) { unsigned v = chunkT[t]; chunkT[t] = r; r += v; }
        }
        __syncthreads();
        {
            int base = tid * 4;
            unsigned add = chunkT[tid];
            #pragma unroll
            for (int k = 0; k < 4; ++k) {
                int idx = base + k;
                if (idx < NB) hist[idx] += add;
            }
        }
        __syncthreads();

        for (int b = tid; b < NB; b += 256) {
            unsigned st = hist[b];
            unsigned en = (b == NB - 1) ? (unsigned)n_this : hist[b + 1];
            unsigned c = en - st;
            gpos[b] = c ? atomicAdd(&cursors[b], c) : 0u;
            curs[b] = 0;
        }
        __syncthreads();

        #pragma unroll
        for (int k = 0; k < 4; ++k) {
            int q = k * 256 + tid;
            if (q < nq) {
                #pragma unroll
                for (int j = 0; j < 4; ++j) {
                    int dd = dv[k][j], ss = sv[k][j];
                    int b = dd >> SBITS;
                    unsigned p = hist[b] + atomicAdd(&curs[b], 1u);
                    srec[p] = make_uint2(((unsigned)(dd & (S_BUCKET - 1)) << 20) | (unsigned)ss,
                                         __float_as_uint(wv[k][j]));
                    sbkt[p] = (unsigned short)b;
                }
            }
        }
        __syncthreads();

        for (int i = tid; i < n_this; i += 256) {
            unsigned b = sbkt[i];
            rec[gpos[b] + ((unsigned)i - hist[b])] = srec[i];
        }
        __syncthreads();
    }
}

// ---------------- pass 2a: per-(super,window) counts ----------------

__global__ __launch_bounds__(256) void count_bins(
    const uint2* __restrict__ rec, const unsigned* __restrict__ cursors,
    unsigned* __restrict__ cnt2) {
    __shared__ unsigned hist[NWIN];
    int tid = threadIdx.x;
    int b = blockIdx.x >> 2, q = blockIdx.x & 3;
    for (int i = tid; i < NWIN; i += 256) hist[i] = 0;
    __syncthreads();
    unsigned cnt = cursors[b] - (unsigned)b * CAP;
    unsigned lo = (unsigned)(((unsigned long long)cnt * (unsigned)q) >> 2);
    unsigned hi = (q == 3) ? cnt : (unsigned)(((unsigned long long)cnt * (unsigned)(q + 1)) >> 2);
    const uint2v* bp = reinterpret_cast<const uint2v*>(rec + (size_t)b * CAP);
    unsigned i = lo + (unsigned)tid;
    for (; i + 768 < hi; i += 1024) {
        uint2v r0 = __builtin_nontemporal_load(bp + i);
        uint2v r1 = __builtin_nontemporal_load(bp + i + 256);
        uint2v r2 = __builtin_nontemporal_load(bp + i + 512);
        uint2v r3 = __builtin_nontemporal_load(bp + i + 768);
        atomicAdd(&hist[(r0.x & 0xFFFFFu) >> 12], 1u);
        atomicAdd(&hist[(r1.x & 0xFFFFFu) >> 12], 1u);
        atomicAdd(&hist[(r2.x & 0xFFFFFu) >> 12], 1u);
        atomicAdd(&hist[(r3.x & 0xFFFFFu) >> 12], 1u);
    }
    for (; i < hi; i += 256) {
        uint2v r = __builtin_nontemporal_load(bp + i);
        atomicAdd(&hist[(r.x & 0xFFFFFu) >> 12], 1u);
    }
    __syncthreads();
    unsigned base = (unsigned)(b / SUP_B) * (unsigned)NWIN;
    for (int k = tid; k < NWIN; k += 256)
        if (hist[k]) atomicAdd(&cnt2[base + k], hist[k]);
}

// ---------------- pass 2b: exclusive prefix over 10045 bins ----------------

__global__ __launch_bounds__(256) void prefix_bins(
    const unsigned* __restrict__ cnt2, unsigned* __restrict__ bases,
    unsigned* __restrict__ cursors2) {
    __shared__ unsigned chunkT[256];
    int t = threadIdx.x;
    unsigned loc[40];
    unsigned run = 0;
    for (int k = 0; k < 40; ++k) {
        int idx = t * 40 + k;
        unsigned v = (idx < NBINS2) ? cnt2[idx] : 0u;
        loc[k] = run; run += v;
    }
    chunkT[t] = run;
    __syncthreads();
    if (t == 0) {
        unsigned r = 0;
        for (int i = 0; i < 256; ++i) { unsigned v = chunkT[i]; chunkT[i] = r; r += v; }
    }
    __syncthreads();
    unsigned add = chunkT[t];
    for (int k = 0; k < 40; ++k) {
        int idx = t * 40 + k;
        if (idx < NBINS2) { unsigned v = loc[k] + add; bases[idx] = v; cursors2[idx] = v; }
    }
    if (t == 0) bases[NBINS2] = (unsigned)NEDGE;
}

// ---------------- pass 2c: regroup into compact (super,window) segments ----------------
// meta2 = rdst(15b)<<12 | src_local(12b); rdst = (b%6)*4096 + dst_local.
// FLAT (bucket,tile) index: round-15 iterated buckets serially with only
// ~32/1024 blocks active (2% occupancy, 1596us). All blocks active now.

__global__ __launch_bounds__(256) void regroup(
    const uint2* __restrict__ rec, const unsigned* __restrict__ cursors,
    uint2* __restrict__ rec2, unsigned* __restrict__ cursors2) {
    __shared__ uint2 srec[TILE];              // transformed records
    __shared__ unsigned char skey[TILE];
    __shared__ unsigned hist[NWIN];
    __shared__ unsigned curs[NWIN];
    __shared__ unsigned gpos[NWIN];
    __shared__ unsigned chunkT[256];
    int tid = threadIdx.x;

    for (int ti = blockIdx.x; ti < NB * MT; ti += gridDim.x) {
        int b = ti / MT;
        unsigned t = (unsigned)(ti % MT);
        unsigned cntb = cursors[b] - (unsigned)b * CAP;
        unsigned e0 = t * TILE;
        if (e0 >= cntb) continue;               // uniform per block
        unsigned n_this = (cntb - e0 < TILE) ? (cntb - e0) : TILE;
        unsigned binbase = (unsigned)(b / SUP_B) * (unsigned)NWIN;
        unsigned rb = (unsigned)(b % SUP_B) << 12;
        const uint2* bp = rec + (size_t)b * CAP;

        for (int i = tid; i < NWIN; i += 256) hist[i] = 0;
        __syncthreads();

        uint4v rv[8];                      // 16 records/thread
        #pragma unroll
        for (int k2 = 0; k2 < 8; ++k2) {
            unsigned idx = (unsigned)(k2 * 512 + tid * 2);
            if (idx < n_this)
                rv[k2] = __builtin_nontemporal_load(
                    reinterpret_cast<const uint4v*>(bp + e0 + idx));
        }
        #pragma unroll
        for (int k2 = 0; k2 < 8; ++k2) {
            unsigned idx = (unsigned)(k2 * 512 + tid * 2);
            if (idx < n_this)     atomicAdd(&hist[(rv[k2].x & 0xFFFFFu) >> 12], 1u);
            if (idx + 1 < n_this) atomicAdd(&hist[(rv[k2].z & 0xFFFFFu) >> 12], 1u);
        }
        __syncthreads();

        chunkT[tid] = (tid < NWIN) ? hist[tid] : 0u;
        __syncthreads();
        if (tid == 0) {
            unsigned r = 0;
            for (int i = 0; i < 256; ++i) { unsigned v = chunkT[i]; chunkT[i] = r; r += v; }
        }
        __syncthreads();
        if (tid < NWIN) hist[tid] = chunkT[tid];
        __syncthreads();
        if (tid < NWIN) {
            unsigned st = hist[tid];
            unsigned en = (tid == NWIN - 1) ? n_this : hist[tid + 1];
            unsigned c = en - st;
            gpos[tid] = c ? atomicAdd(&cursors2[binbase + tid], c) : 0u;
            curs[tid] = 0;
        }
        __syncthreads();

        #pragma unroll
        for (int k2 = 0; k2 < 8; ++k2) {
            unsigned idx = (unsigned)(k2 * 512 + tid * 2);
            if (idx < n_this) {
                unsigned m = rv[k2].x;
                unsigned k = (m & 0xFFFFFu) >> 12;
                unsigned p = hist[k] + atomicAdd(&curs[k], 1u);
                srec[p] = make_uint2((((m >> 20) + rb) << 12) | (m & 0xFFFu), rv[k2].y);
                skey[p] = (unsigned char)k;
            }
            if (idx + 1 < n_this) {
                unsigned m = rv[k2].z;
                unsigned k = (m & 0xFFFFFu) >> 12;
                unsigned p = hist[k] + atomicAdd(&curs[k], 1u);
                srec[p] = make_uint2((((m >> 20) + rb) << 12) | (m & 0xFFFu), rv[k2].w);
                skey[p] = (unsigned char)k;
            }
        }
        __syncthreads();

        for (unsigned i = (unsigned)tid; i < n_this; i += 256) {
            unsigned k = skey[i];
            rec2[gpos[k] + (i - hist[k])] = srec[i];
        }
        __syncthreads();
    }
}

// ---------------- LDS-gather hop: double-buffered window, 1 barrier/window ----------------

__global__ __launch_bounds__(512) void hop_super(
    const uint2* __restrict__ rec2, const unsigned* __restrict__ bases,
    const float* __restrict__ cur, float* __restrict__ nxt) {
    __shared__ float acc[S_SUPER];     // 96KB
    __shared__ float win[2][4096];     // 32KB double buffer
    int tid = threadIdx.x;
    int s = blockIdx.x / HSPLIT;
    int j = blockIdx.x % HSPLIT;
    for (int i = tid; i < S_SUPER; i += 512) acc[i] = 0.0f;

    float pf[8];
    {   // prologue: stage first window into win[0]
        int wbase = j << 12;
        #pragma unroll
        for (int q = 0; q < 8; ++q) {
            int g = wbase + q * 512 + tid;
            pf[q] = (g < N_USERS) ? cur[g] : 0.0f;
        }
        #pragma unroll
        for (int q = 0; q < 8; ++q) win[0][q * 512 + tid] = pf[q];
    }
    int cb = 0;
    for (int k = j; k < NWIN; k += HSPLIT) {
        __syncthreads();                 // win[cb] staged; acc-init/prev done

        int kn = k + HSPLIT;             // prefetch next window into regs
        if (kn < NWIN) {
            int wbase = kn << 12;
            #pragma unroll
            for (int q = 0; q < 8; ++q) {
                int g = wbase + q * 512 + tid;
                pf[q] = (g < N_USERS) ? cur[g] : 0.0f;
            }
        }

        unsigned lo = bases[s * NWIN + k];
        unsigned hi = bases[s * NWIN + k + 1];
        if ((lo & 1u) && lo < hi) {      // align to 16B
            if (tid == 0) {
                uint2 r = rec2[lo];
                atomicAdd(&acc[r.x >> 12], win[cb][r.x & 0xFFFu] * __uint_as_float(r.y));
            }
            ++lo;
        }
        for (unsigned i = lo + 2u * (unsigned)tid; i + 2u <= hi; i += 2u * 512u) {
            uint4v a = __builtin_nontemporal_load(reinterpret_cast<const uint4v*>(rec2 + i));
            float v0 = win[cb][a.x & 0xFFFu];
            float v1 = win[cb][a.z & 0xFFFu];
            atomicAdd(&acc[a.x >> 12], v0 * __uint_as_float(a.y));
            atomicAdd(&acc[a.z >> 12], v1 * __uint_as_float(a.w));
        }
        if (((hi - lo) & 1u) && tid == 0 && hi > lo) {
            uint2 r = rec2[hi - 1];
            atomicAdd(&acc[r.x >> 12], win[cb][r.x & 0xFFFu] * __uint_as_float(r.y));
        }

        if (kn < NWIN) {                 // write next window (distinct buffer: no barrier)
            #pragma unroll
            for (int q = 0; q < 8; ++q) win[cb ^ 1][q * 512 + tid] = pf[q];
        }
        cb ^= 1;
    }
    __syncthreads();
    int d0 = s * S_SUPER;
    for (int i = tid; i < S_SUPER; i += 512) {
        int n = d0 + i;
        if (n < N_USERS) atomicAdd(&nxt[n], acc[i]);
    }
}

// ---------------- fallback path ----------------

__global__ void zero_kernel(float* __restrict__ p, int n) {
    int i = blockIdx.x * blockDim.x + threadIdx.x;
    int stride = gridDim.x * blockDim.x;
    for (; i < n; i += stride) p[i] = 0.0f;
}

__global__ __launch_bounds__(256) void hop_atomic(
    const int* __restrict__ src, const int* __restrict__ dst,
    const float* __restrict__ ew, const float* __restrict__ cur,
    float* __restrict__ nxt) {
    int e = blockIdx.x * blockDim.x + threadIdx.x;
    if (e * 4 < NEDGE) {
        int4   s = ((const int4*)src)[e];
        int4   d = ((const int4*)dst)[e];
        float4 w = ((const float4*)ew)[e];
        atomicAdd(&nxt[d.x], cur[s.x] * w.x);
        atomicAdd(&nxt[d.y], cur[s.y] * w.y);
        atomicAdd(&nxt[d.z], cur[s.z] * w.z);
        atomicAdd(&nxt[d.w], cur[s.w] * w.w);
    }
}

// ---------------- finalize ----------------

__global__ __launch_bounds__(256) void finalize_kernel(
    const float* __restrict__ x,  const float* __restrict__ f1,
    const float* __restrict__ f2, const float* __restrict__ f3,
    const float* __restrict__ f4, const float* __restrict__ W,
    const float* __restrict__ bias, const float* __restrict__ gamma,
    const float* __restrict__ beta, float* __restrict__ out) {
    int lane = threadIdx.x & 63;
    int waveInBlock = threadIdx.x >> 6;
    int wavesPerBlock = blockDim.x >> 6;
    int gwave  = blockIdx.x * wavesPerBlock + waveInBlock;
    int nwaves = gridDim.x * wavesPerBlock;

    float w0 = W[lane * 5 + 0];
    float w1 = W[lane * 5 + 1];
    float w2 = W[lane * 5 + 2];
    float w3 = W[lane * 5 + 3];
    float w4 = W[lane * 5 + 4];
    float b  = bias[lane];

    for (int n = gwave; n < N_USERS; n += nwaves) {
        float c0 = x[n], c1 = f1[n], c2 = f2[n], c3 = f3[n], c4 = f4[n];
        float y = b + c0 * w0 + c1 * w1 + c2 * w2 + c3 * w3 + c4 * w4;

        float s = y;
        #pragma unroll
        for (int off = 32; off; off >>= 1) s += __shfl_xor(s, off);
        float mean = s * (1.0f / 64.0f);

        float d = y - mean;
        float v = d * d;
        #pragma unroll
        for (int off = 32; off; off >>= 1) v += __shfl_xor(v, off);
        float var = v * (1.0f / 64.0f);

        float o = d * rsqrtf(var + BN_EPS) * gamma[n] + beta[n];
        __builtin_nontemporal_store(o, &out[(size_t)n * OUT_F + lane]);
    }
}

extern "C" void kernel_launch(void* const* d_in, const int* in_sizes, int n_in,
                              void* d_out, int out_size, void* d_ws, size_t ws_size,
                              hipStream_t stream) {
    const float* x     = (const float*)d_in[0];
    const int*   ei    = (const int*)d_in[1];
    const float* ew    = (const float*)d_in[2];
    const float* W     = (const float*)d_in[3];
    const float* bias  = (const float*)d_in[4];
    const float* gamma = (const float*)d_in[5];
    const float* beta  = (const float*)d_in[6];
    float* out = (float*)d_out;

    const int* src = ei;
    const int* dst = ei + NEDGE;

    // Workspace layout (~284.5MB; known-available >= 304MB from rounds 0-1)
    float* f = (float*)d_ws;                                     // 16MB
    uint2* rec = (uint2*)(f + 4ull * N_USERS);                   // 268.3MB
    unsigned* cursors  = (unsigned*)(rec + (size_t)NB * CAP);    // pad 1024
    unsigned* cnt2     = cursors + 1024;                         // pad 10240
    unsigned* bases    = cnt2 + 10240;                           // NBINS2+1, pad 10240
    unsigned* cursors2 = bases + 10240;                          // pad 10240
    size_t needed = 16000000ull + (size_t)NB * CAP * 8 + 4096 + 3ull * 40960;

    // Regrouped compact records live in d_out (dead until finalize).
    uint2* rec2 = (uint2*)d_out;

    if (ws_size >= needed) {
        init_cursors<<<1, 256, 0, stream>>>(cursors);
        zero_kernel<<<2048, 256, 0, stream>>>(f, 4 * N_USERS);      // hop flush is atomicAdd
        zero_kernel<<<40, 256, 0, stream>>>((float*)cnt2, NBINS2);  // bit-zero uints
        scatter_bin<<<SCAT_BLOCKS, 256, 0, stream>>>(src, dst, ew, rec, cursors);
        count_bins<<<NB * 4, 256, 0, stream>>>(rec, cursors, cnt2);
        prefix_bins<<<1, 256, 0, stream>>>(cnt2, bases, cursors2);
        regroup<<<RGRID, 256, 0, stream>>>(rec, cursors, rec2, cursors2);
        const float* cur = x;
        for (int h = 0; h < 4; ++h) {
            float* nxt = f + (size_t)h * N_USERS;
            hop_super<<<NSUP * HSPLIT, 512, 0, stream>>>(rec2, bases, cur, nxt);
            cur = nxt;
        }
    } else {
        zero_kernel<<<4096, 256, 0, stream>>>(f, 4 * N_USERS);
        const float* cur = x;
        for (int h = 0; h < 4; ++h) {
            float* nxt = f + (size_t)h * N_USERS;
            hop_atomic<<<NEDGE / 4 / 256, 256, 0, stream>>>(src, dst, ew, cur, nxt);
            cur = nxt;
        }
    }

    finalize_kernel<<<2048, 256, 0, stream>>>(
        x, f, f + N_USERS, f + 2 * N_USERS, f + 3 * N_USERS,
        W, bias, gamma, beta, out);
}

// Round 17
// 1700.348 us; speedup vs baseline: 2.0906x; 1.0749x over previous
//
#include <hip/hip_runtime.h>

#define N_USERS 1000000
#define NEDGE   32000000
#define OUT_F   64
#define BN_EPS  1e-5f

// ---- Pass 1 (proven round-12 scatter): 245 dst-buckets of 4096 ----
#define SBITS     12
#define S_BUCKET  4096
#define NB        245
#define CAP       136896                  // mean 130612 + ~17 sigma, mult of 16
#define SCAT_BLOCKS 1024
#define TILE      4096
#define NTILES    ((NEDGE + TILE - 1) / TILE)

// ---- Pass 2 (regroup): super-buckets x src-windows ----
// Hop exploits the regrouped layout differently from round 16: a wave owns
// whole (super,window) cells, so its ~3200 gathers fall in ONE 16KB window of
// cur -> L1-resident (~12.5 reuses/line). No LDS window staging, no barriers
// in the main loop. Round-16's LDS-staged variant merely swapped gather
// misses for equal staging traffic (FETCH 135MB = NSUP*4MB) at 233us.
#define SUP_B     6                       // pass-1 buckets per super
#define NSUP      41                      // ceil(245/6)
#define S_SUPER   24576                   // dst nodes per super (acc = 96KB LDS)
#define NWIN      245                     // src windows of 4096 (src>>12)
#define NBINS2    (NSUP * NWIN)           // 10045
#define HSPLIT    6                       // blocks per super in the hop
#define RGRID     1024
#define MT        34                      // max tiles per bucket (34*4096 >= CAP)

static_assert((unsigned long long)NEDGE * 8ull ==
              (unsigned long long)N_USERS * OUT_F * 4ull,
              "compact rec2 must exactly fit d_out");

typedef unsigned int uint4v __attribute__((ext_vector_type(4)));
typedef unsigned int uint2v __attribute__((ext_vector_type(2)));
typedef int          int4v  __attribute__((ext_vector_type(4)));
typedef float        flt4v  __attribute__((ext_vector_type(4)));

// ---------------- pass 1: binned scatter (unchanged from round 12) ----------------

__global__ void init_cursors(unsigned* __restrict__ cursors) {
    int i = blockIdx.x * blockDim.x + threadIdx.x;
    if (i < NB) cursors[i] = (unsigned)i * CAP;
}

__global__ __launch_bounds__(256) void scatter_bin(
    const int* __restrict__ src, const int* __restrict__ dst,
    const float* __restrict__ ew, uint2* __restrict__ rec,
    unsigned* __restrict__ cursors) {
    __shared__ uint2 srec[TILE];
    __shared__ unsigned short sbkt[TILE];
    __shared__ unsigned hist[NB];
    __shared__ unsigned curs[NB];
    __shared__ unsigned gpos[NB];
    __shared__ unsigned chunkT[256];
    int tid = threadIdx.x;

    for (int tile = blockIdx.x; tile < NTILES; tile += gridDim.x) {
        int e0 = tile * TILE;
        int n_this = (e0 + TILE <= NEDGE) ? TILE : (NEDGE - e0);
        int nq = n_this >> 2;
        int q0 = e0 >> 2;

        for (int i = tid; i < NB; i += 256) hist[i] = 0;
        __syncthreads();

        int4v dv[4]; int4v sv[4]; flt4v wv[4];
        #pragma unroll
        for (int k = 0; k < 4; ++k) {
            int q = k * 256 + tid;
            if (q < nq) {
                dv[k] = __builtin_nontemporal_load(reinterpret_cast<const int4v*>(dst) + q0 + q);
                sv[k] = __builtin_nontemporal_load(reinterpret_cast<const int4v*>(src) + q0 + q);
                wv[k] = __builtin_nontemporal_load(reinterpret_cast<const flt4v*>(ew) + q0 + q);
            }
        }
        #pragma unroll
        for (int k = 0; k < 4; ++k) {
            int q = k * 256 + tid;
            if (q < nq) {
                #pragma unroll
                for (int j = 0; j < 4; ++j)
                    atomicAdd(&hist[dv[k][j] >> SBITS], 1u);
            }
        }
        __syncthreads();

        {
            int base = tid * 4;
            unsigned run = 0;
            #pragma unroll
            for (int k = 0; k < 4; ++k) {
                int idx = base + k;
                unsigned v = (idx < NB) ? hist[idx] : 0u;
                if (idx < NB) hist[idx] = run;
                run += v;
            }
            chunkT[tid] = run;
        }
        __syncthreads();
        if (tid == 0) {
            unsigned r = 0;
            for (int t = 0; t < 256; ++t) { unsigned v = chunkT[t]; chunkT[t] = r; r += v; }
        }
        __syncthreads();
        {
            int base = tid * 4;
            unsigned add = chunkT[tid];
            #pragma unroll
            for (int k = 0; k < 4; ++k) {
                int idx = base + k;
                if (idx < NB) hist[idx] += add;
            }
        }
        __syncthreads();

        for (int b = tid; b < NB; b += 256) {
            unsigned st = hist[b];
            unsigned en = (b == NB - 1) ? (unsigned)n_this : hist[b + 1];
            unsigned c = en - st;
            gpos[b] = c ? atomicAdd(&cursors[b], c) : 0u;
            curs[b] = 0;
        }
        __syncthreads();

        #pragma unroll
        for (int k = 0; k < 4; ++k) {
            int q = k * 256 + tid;
            if (q < nq) {
                #pragma unroll
                for (int j = 0; j < 4; ++j) {
                    int dd = dv[k][j], ss = sv[k][j];
                    int b = dd >> SBITS;
                    unsigned p = hist[b] + atomicAdd(&curs[b], 1u);
                    srec[p] = make_uint2(((unsigned)(dd & (S_BUCKET - 1)) << 20) | (unsigned)ss,
                                         __float_as_uint(wv[k][j]));
                    sbkt[p] = (unsigned short)b;
                }
            }
        }
        __syncthreads();

        for (int i = tid; i < n_this; i += 256) {
            unsigned b = sbkt[i];
            rec[gpos[b] + ((unsigned)i - hist[b])] = srec[i];
        }
        __syncthreads();
    }
}

// ---------------- pass 2a: per-(super,window) counts ----------------

__global__ __launch_bounds__(256) void count_bins(
    const uint2* __restrict__ rec, const unsigned* __restrict__ cursors,
    unsigned* __restrict__ cnt2) {
    __shared__ unsigned hist[NWIN];
    int tid = threadIdx.x;
    int b = blockIdx.x >> 2, q = blockIdx.x & 3;
    for (int i = tid; i < NWIN; i += 256) hist[i] = 0;
    __syncthreads();
    unsigned cnt = cursors[b] - (unsigned)b * CAP;
    unsigned lo = (unsigned)(((unsigned long long)cnt * (unsigned)q) >> 2);
    unsigned hi = (q == 3) ? cnt : (unsigned)(((unsigned long long)cnt * (unsigned)(q + 1)) >> 2);
    const uint2v* bp = reinterpret_cast<const uint2v*>(rec + (size_t)b * CAP);
    unsigned i = lo + (unsigned)tid;
    for (; i + 768 < hi; i += 1024) {
        uint2v r0 = __builtin_nontemporal_load(bp + i);
        uint2v r1 = __builtin_nontemporal_load(bp + i + 256);
        uint2v r2 = __builtin_nontemporal_load(bp + i + 512);
        uint2v r3 = __builtin_nontemporal_load(bp + i + 768);
        atomicAdd(&hist[(r0.x & 0xFFFFFu) >> 12], 1u);
        atomicAdd(&hist[(r1.x & 0xFFFFFu) >> 12], 1u);
        atomicAdd(&hist[(r2.x & 0xFFFFFu) >> 12], 1u);
        atomicAdd(&hist[(r3.x & 0xFFFFFu) >> 12], 1u);
    }
    for (; i < hi; i += 256) {
        uint2v r = __builtin_nontemporal_load(bp + i);
        atomicAdd(&hist[(r.x & 0xFFFFFu) >> 12], 1u);
    }
    __syncthreads();
    unsigned base = (unsigned)(b / SUP_B) * (unsigned)NWIN;
    for (int k = tid; k < NWIN; k += 256)
        if (hist[k]) atomicAdd(&cnt2[base + k], hist[k]);
}

// ---------------- pass 2b: exclusive prefix over 10045 bins ----------------

__global__ __launch_bounds__(256) void prefix_bins(
    const unsigned* __restrict__ cnt2, unsigned* __restrict__ bases,
    unsigned* __restrict__ cursors2) {
    __shared__ unsigned chunkT[256];
    int t = threadIdx.x;
    unsigned loc[40];
    unsigned run = 0;
    for (int k = 0; k < 40; ++k) {
        int idx = t * 40 + k;
        unsigned v = (idx < NBINS2) ? cnt2[idx] : 0u;
        loc[k] = run; run += v;
    }
    chunkT[t] = run;
    __syncthreads();
    if (t == 0) {
        unsigned r = 0;
        for (int i = 0; i < 256; ++i) { unsigned v = chunkT[i]; chunkT[i] = r; r += v; }
    }
    __syncthreads();
    unsigned add = chunkT[t];
    for (int k = 0; k < 40; ++k) {
        int idx = t * 40 + k;
        if (idx < NBINS2) { unsigned v = loc[k] + add; bases[idx] = v; cursors2[idx] = v; }
    }
    if (t == 0) bases[NBINS2] = (unsigned)NEDGE;
}

// ---------------- pass 2c: regroup into compact (super,window) segments ----------------
// meta2 = rdst(15b)<<12 | src_local(12b); rdst = (b%6)*4096 + dst_local.

__global__ __launch_bounds__(256) void regroup(
    const uint2* __restrict__ rec, const unsigned* __restrict__ cursors,
    uint2* __restrict__ rec2, unsigned* __restrict__ cursors2) {
    __shared__ uint2 srec[TILE];              // transformed records
    __shared__ unsigned char skey[TILE];
    __shared__ unsigned hist[NWIN];
    __shared__ unsigned curs[NWIN];
    __shared__ unsigned gpos[NWIN];
    __shared__ unsigned chunkT[256];
    int tid = threadIdx.x;

    for (int ti = blockIdx.x; ti < NB * MT; ti += gridDim.x) {
        int b = ti / MT;
        unsigned t = (unsigned)(ti % MT);
        unsigned cntb = cursors[b] - (unsigned)b * CAP;
        unsigned e0 = t * TILE;
        if (e0 >= cntb) continue;               // uniform per block
        unsigned n_this = (cntb - e0 < TILE) ? (cntb - e0) : TILE;
        unsigned binbase = (unsigned)(b / SUP_B) * (unsigned)NWIN;
        unsigned rb = (unsigned)(b % SUP_B) << 12;
        const uint2* bp = rec + (size_t)b * CAP;

        for (int i = tid; i < NWIN; i += 256) hist[i] = 0;
        __syncthreads();

        uint4v rv[8];                      // 16 records/thread
        #pragma unroll
        for (int k2 = 0; k2 < 8; ++k2) {
            unsigned idx = (unsigned)(k2 * 512 + tid * 2);
            if (idx < n_this)
                rv[k2] = __builtin_nontemporal_load(
                    reinterpret_cast<const uint4v*>(bp + e0 + idx));
        }
        #pragma unroll
        for (int k2 = 0; k2 < 8; ++k2) {
            unsigned idx = (unsigned)(k2 * 512 + tid * 2);
            if (idx < n_this)     atomicAdd(&hist[(rv[k2].x & 0xFFFFFu) >> 12], 1u);
            if (idx + 1 < n_this) atomicAdd(&hist[(rv[k2].z & 0xFFFFFu) >> 12], 1u);
        }
        __syncthreads();

        chunkT[tid] = (tid < NWIN) ? hist[tid] : 0u;
        __syncthreads();
        if (tid == 0) {
            unsigned r = 0;
            for (int i = 0; i < 256; ++i) { unsigned v = chunkT[i]; chunkT[i] = r; r += v; }
        }
        __syncthreads();
        if (tid < NWIN) hist[tid] = chunkT[tid];
        __syncthreads();
        if (tid < NWIN) {
            unsigned st = hist[tid];
            unsigned en = (tid == NWIN - 1) ? n_this : hist[tid + 1];
            unsigned c = en - st;
            gpos[tid] = c ? atomicAdd(&cursors2[binbase + tid], c) : 0u;
            curs[tid] = 0;
        }
        __syncthreads();

        #pragma unroll
        for (int k2 = 0; k2 < 8; ++k2) {
            unsigned idx = (unsigned)(k2 * 512 + tid * 2);
            if (idx < n_this) {
                unsigned m = rv[k2].x;
                unsigned k = (m & 0xFFFFFu) >> 12;
                unsigned p = hist[k] + atomicAdd(&curs[k], 1u);
                srec[p] = make_uint2((((m >> 20) + rb) << 12) | (m & 0xFFFu), rv[k2].y);
                skey[p] = (unsigned char)k;
            }
            if (idx + 1 < n_this) {
                unsigned m = rv[k2].z;
                unsigned k = (m & 0xFFFFFu) >> 12;
                unsigned p = hist[k] + atomicAdd(&curs[k], 1u);
                srec[p] = make_uint2((((m >> 20) + rb) << 12) | (m & 0xFFFu), rv[k2].w);
                skey[p] = (unsigned char)k;
            }
        }
        __syncthreads();

        for (unsigned i = (unsigned)tid; i < n_this; i += 256) {
            unsigned k = skey[i];
            rec2[gpos[k] + (i - hist[k])] = srec[i];
        }
        __syncthreads();
    }
}

// ---------------- hop: wave-private windows, direct L1-resident gathers ----------------
// Each wave owns whole (super,window) cells: its gathers stay in one 16KB
// window of cur (L1-resident, ~12.5 reuses/line). No barriers in main loop;
// acc shared across waves via ds_add atomics. 8 records in flight per lane.

__global__ __launch_bounds__(512) void hop_super(
    const uint2* __restrict__ rec2, const unsigned* __restrict__ bases,
    const float* __restrict__ cur, float* __restrict__ nxt) {
    __shared__ float acc[S_SUPER];     // 96KB
    int tid = threadIdx.x;
    int s = blockIdx.x / HSPLIT;
    int j = blockIdx.x % HSPLIT;
    for (int i = tid; i < S_SUPER; i += 512) acc[i] = 0.0f;
    __syncthreads();

    int wid = tid >> 6;                // wave 0..7
    int lane = tid & 63;
    int slot = j * 8 + wid;            // 0..47 wave-slots per super
    const unsigned* bs = bases + s * NWIN;

    for (int k = slot; k < NWIN; k += HSPLIT * 8) {
        unsigned lo = bs[k];
        unsigned hi = bs[k + 1];       // flat prefix: valid sentinel for all k
        const float* win = cur + ((size_t)k << 12);
        unsigned i = lo + (unsigned)lane;
        for (; i + 7u * 64u < hi; i += 8u * 64u) {
            uint2 r0 = rec2[i];
            uint2 r1 = rec2[i + 64];
            uint2 r2 = rec2[i + 128];
            uint2 r3 = rec2[i + 192];
            uint2 r4 = rec2[i + 256];
            uint2 r5 = rec2[i + 320];
            uint2 r6 = rec2[i + 384];
            uint2 r7 = rec2[i + 448];
            float c0 = win[r0.x & 0xFFFu];
            float c1 = win[r1.x & 0xFFFu];
            float c2 = win[r2.x & 0xFFFu];
            float c3 = win[r3.x & 0xFFFu];
            float c4 = win[r4.x & 0xFFFu];
            float c5 = win[r5.x & 0xFFFu];
            float c6 = win[r6.x & 0xFFFu];
            float c7 = win[r7.x & 0xFFFu];
            atomicAdd(&acc[r0.x >> 12], c0 * __uint_as_float(r0.y));
            atomicAdd(&acc[r1.x >> 12], c1 * __uint_as_float(r1.y));
            atomicAdd(&acc[r2.x >> 12], c2 * __uint_as_float(r2.y));
            atomicAdd(&acc[r3.x >> 12], c3 * __uint_as_float(r3.y));
            atomicAdd(&acc[r4.x >> 12], c4 * __uint_as_float(r4.y));
            atomicAdd(&acc[r5.x >> 12], c5 * __uint_as_float(r5.y));
            atomicAdd(&acc[r6.x >> 12], c6 * __uint_as_float(r6.y));
            atomicAdd(&acc[r7.x >> 12], c7 * __uint_as_float(r7.y));
        }
        for (; i < hi; i += 64u) {
            uint2 r = rec2[i];
            atomicAdd(&acc[r.x >> 12], win[r.x & 0xFFFu] * __uint_as_float(r.y));
        }
    }
    __syncthreads();
    int d0 = s * S_SUPER;
    for (int i = tid; i < S_SUPER; i += 512) {
        int n = d0 + i;
        if (n < N_USERS) atomicAdd(&nxt[n], acc[i]);
    }
}

// ---------------- fallback path ----------------

__global__ void zero_kernel(float* __restrict__ p, int n) {
    int i = blockIdx.x * blockDim.x + threadIdx.x;
    int stride = gridDim.x * blockDim.x;
    for (; i < n; i += stride) p[i] = 0.0f;
}

__global__ __launch_bounds__(256) void hop_atomic(
    const int* __restrict__ src, const int* __restrict__ dst,
    const float* __restrict__ ew, const float* __restrict__ cur,
    float* __restrict__ nxt) {
    int e = blockIdx.x * blockDim.x + threadIdx.x;
    if (e * 4 < NEDGE) {
        int4   s = ((const int4*)src)[e];
        int4   d = ((const int4*)dst)[e];
        float4 w = ((const float4*)ew)[e];
        atomicAdd(&nxt[d.x], cur[s.x] * w.x);
        atomicAdd(&nxt[d.y], cur[s.y] * w.y);
        atomicAdd(&nxt[d.z], cur[s.z] * w.z);
        atomicAdd(&nxt[d.w], cur[s.w] * w.w);
    }
}

// ---------------- finalize ----------------

__global__ __launch_bounds__(256) void finalize_kernel(
    const float* __restrict__ x,  const float* __restrict__ f1,
    const float* __restrict__ f2, const float* __restrict__ f3,
    const float* __restrict__ f4, const float* __restrict__ W,
    const float* __restrict__ bias, const float* __restrict__ gamma,
    const float* __restrict__ beta, float* __restrict__ out) {
    int lane = threadIdx.x & 63;
    int waveInBlock = threadIdx.x >> 6;
    int wavesPerBlock = blockDim.x >> 6;
    int gwave  = blockIdx.x * wavesPerBlock + waveInBlock;
    int nwaves = gridDim.x * wavesPerBlock;

    float w0 = W[lane * 5 + 0];
    float w1 = W[lane * 5 + 1];
    float w2 = W[lane * 5 + 2];
    float w3 = W[lane * 5 + 3];
    float w4 = W[lane * 5 + 4];
    float b  = bias[lane];

    for (int n = gwave; n < N_USERS; n += nwaves) {
        float c0 = x[n], c1 = f1[n], c2 = f2[n], c3 = f3[n], c4 = f4[n];
        float y = b + c0 * w0 + c1 * w1 + c2 * w2 + c3 * w3 + c4 * w4;

        float s = y;
        #pragma unroll
        for (int off = 32; off; off >>= 1) s += __shfl_xor(s, off);
        float mean = s * (1.0f / 64.0f);

        float d = y - mean;
        float v = d * d;
        #pragma unroll
        for (int off = 32; off; off >>= 1) v += __shfl_xor(v, off);
        float var = v * (1.0f / 64.0f);

        float o = d * rsqrtf(var + BN_EPS) * gamma[n] + beta[n];
        __builtin_nontemporal_store(o, &out[(size_t)n * OUT_F + lane]);
    }
}

extern "C" void kernel_launch(void* const* d_in, const int* in_sizes, int n_in,
                              void* d_out, int out_size, void* d_ws, size_t ws_size,
                              hipStream_t stream) {
    const float* x     = (const float*)d_in[0];
    const int*   ei    = (const int*)d_in[1];
    const float* ew    = (const float*)d_in[2];
    const float* W     = (const float*)d_in[3];
    const float* bias  = (const float*)d_in[4];
    const float* gamma = (const float*)d_in[5];
    const float* beta  = (const float*)d_in[6];
    float* out = (float*)d_out;

    const int* src = ei;
    const int* dst = ei + NEDGE;

    // Workspace layout (~284.5MB; known-available >= 304MB from rounds 0-1)
    float* f = (float*)d_ws;                                     // 16MB
    uint2* rec = (uint2*)(f + 4ull * N_USERS);                   // 268.3MB
    unsigned* cursors  = (unsigned*)(rec + (size_t)NB * CAP);    // pad 1024
    unsigned* cnt2     = cursors + 1024;                         // pad 10240
    unsigned* bases    = cnt2 + 10240;                           // NBINS2+1, pad 10240
    unsigned* cursors2 = bases + 10240;                          // pad 10240
    size_t needed = 16000000ull + (size_t)NB * CAP * 8 + 4096 + 3ull * 40960;

    // Regrouped compact records live in d_out (dead until finalize).
    uint2* rec2 = (uint2*)d_out;

    if (ws_size >= needed) {
        init_cursors<<<1, 256, 0, stream>>>(cursors);
        zero_kernel<<<2048, 256, 0, stream>>>(f, 4 * N_USERS);      // hop flush is atomicAdd
        zero_kernel<<<40, 256, 0, stream>>>((float*)cnt2, NBINS2);  // bit-zero uints
        scatter_bin<<<SCAT_BLOCKS, 256, 0, stream>>>(src, dst, ew, rec, cursors);
        count_bins<<<NB * 4, 256, 0, stream>>>(rec, cursors, cnt2);
        prefix_bins<<<1, 256, 0, stream>>>(cnt2, bases, cursors2);
        regroup<<<RGRID, 256, 0, stream>>>(rec, cursors, rec2, cursors2);
        const float* cur = x;
        for (int h = 0; h < 4; ++h) {
            float* nxt = f + (size_t)h * N_USERS;
            hop_super<<<NSUP * HSPLIT, 512, 0, stream>>>(rec2, bases, cur, nxt);
            cur = nxt;
        }
    } else {
        zero_kernel<<<4096, 256, 0, stream>>>(f, 4 * N_USERS);
        const float* cur = x;
        for (int h = 0; h < 4; ++h) {
            float* nxt = f + (size_t)h * N_USERS;
            hop_atomic<<<NEDGE / 4 / 256, 256, 0, stream>>>(src, dst, ew, cur, nxt);
            cur = nxt;
        }
    }

    finalize_kernel<<<2048, 256, 0, stream>>>(
        x, f, f + N_USERS, f + 2 * N_USERS, f + 3 * N_USERS,
        W, bias, gamma, beta, out);
}